// Round 1
// baseline (8999.823 us; speedup 1.0000x reference)
//
#include <hip/hip_runtime.h>

#define HID   64
#define SEQ   512
#define BBLK  4
#define GATES 256   // 4*HID
#define NBLK  256   // 1024 batch / BBLK

__device__ __forceinline__ float sig_(float x) { return 1.0f / (1.0f + __expf(-x)); }

// sign-stable tanh: never exponentiates a large positive argument
__device__ __forceinline__ float tanh_(float x) {
    const float e = __expf(-2.0f * fabsf(x));
    const float r = (1.0f - e) / (1.0f + e);
    return copysignf(r, x);
}

// acc[b] += sum_{k<64} h[b*64+k] * Wp[k*256 + j]
__device__ __forceinline__ void mm64(const float* __restrict__ Wp, int j,
                                     const float* __restrict__ h,   // LDS [BBLK][HID]
                                     float acc[BBLK])
{
#pragma unroll
    for (int k = 0; k < HID; k += 4) {
        const float w0 = Wp[(k + 0) * GATES + j];
        const float w1 = Wp[(k + 1) * GATES + j];
        const float w2 = Wp[(k + 2) * GATES + j];
        const float w3 = Wp[(k + 3) * GATES + j];
#pragma unroll
        for (int b = 0; b < BBLK; ++b) {
            const float4 hq = *reinterpret_cast<const float4*>(&h[b * HID + k]);
            acc[b] = fmaf(hq.x, w0, acc[b]);
            acc[b] = fmaf(hq.y, w1, acc[b]);
            acc[b] = fmaf(hq.z, w2, acc[b]);
            acc[b] = fmaf(hq.w, w3, acc[b]);
        }
    }
}

__device__ __forceinline__ float gatephase(const float* __restrict__ zrow, int m, float& c)
{
    const float zi = zrow[m];
    const float zf = zrow[m + 64];
    const float zg = zrow[m + 128];
    const float zo = zrow[m + 192];
    const float ig = sig_(zi), fg = sig_(zf), gg = tanh_(zg), og = sig_(zo);
    c = fmaf(fg, c, ig * gg);
    return og * tanh_(c);
}

__global__ __launch_bounds__(256, 1) void lstm4_f32(
    const float* __restrict__ x,
    const float* __restrict__ W0, const float* __restrict__ B0,
    const float* __restrict__ W1, const float* __restrict__ B1,
    const float* __restrict__ W2, const float* __restrict__ B2,
    const float* __restrict__ W3, const float* __restrict__ B3,
    const float* __restrict__ ln_g, const float* __restrict__ ln_b,
    const float* __restrict__ Wout, const float* __restrict__ bout,
    float* __restrict__ out)
{
    __shared__ float hbuf[4][BBLK][HID];   // per-layer h state
    __shared__ float zbuf[BBLK][GATES];    // gate pre-activations
    __shared__ float xall[BBLK * SEQ];     // this block's x, staged once

    const int j  = threadIdx.x;   // 0..255 : gate column
    const int bb = blockIdx.x;    // 0..255 : batch block
    const int bl = j >> 6;        // wave id == batch lane for gate phase
    const int m  = j & 63;        // hidden index for gate phase

    // stage x (block's 4 batch rows are contiguous: x[b][t], b = bb*4..bb*4+3)
#pragma unroll
    for (int r = 0; r < (BBLK * SEQ) / 256; ++r)
        xall[j + 256 * r] = x[bb * (BBLK * SEQ) + j + 256 * r];

    const float bias0 = B0[j], bias1 = B1[j], bias2 = B2[j], bias3 = B3[j];
    const float wx0 = W0[j];                       // W0 row 0 (x weight)
    const float gam = ln_g[m], bet = ln_b[m], wo = Wout[m], bo = bout[0];

#pragma unroll
    for (int l = 0; l < 4; ++l) hbuf[l][bl][m] = 0.0f;
    float c0 = 0.0f, c1 = 0.0f, c2 = 0.0f, c3 = 0.0f;

    __syncthreads();

    const float* __restrict__ W0h = W0 + GATES;    // W0 rows 1..64 (h weights)

    for (int t = 0; t < SEQ; ++t) {
        float acc[BBLK];

        // ---------------- layer 0 : in = [x_t, h0] ----------------
#pragma unroll
        for (int b = 0; b < BBLK; ++b)
            acc[b] = fmaf(xall[b * SEQ + t], wx0, bias0);
        mm64(W0h, j, &hbuf[0][0][0], acc);
#pragma unroll
        for (int b = 0; b < BBLK; ++b) zbuf[b][j] = acc[b];
        __syncthreads();
        {
            const float hn = gatephase(&zbuf[bl][0], m, c0);
            hbuf[0][bl][m] = hn;
        }
        __syncthreads();

        // ---------------- layer 1 : in = [h0, h1] ----------------
#pragma unroll
        for (int b = 0; b < BBLK; ++b) acc[b] = bias1;
        mm64(W1,              j, &hbuf[0][0][0], acc);
        mm64(W1 + HID * GATES, j, &hbuf[1][0][0], acc);
#pragma unroll
        for (int b = 0; b < BBLK; ++b) zbuf[b][j] = acc[b];
        __syncthreads();
        {
            const float hn = gatephase(&zbuf[bl][0], m, c1);
            hbuf[1][bl][m] = hn;
        }
        __syncthreads();

        // ---------------- layer 2 : in = [h1, h2] ----------------
#pragma unroll
        for (int b = 0; b < BBLK; ++b) acc[b] = bias2;
        mm64(W2,              j, &hbuf[1][0][0], acc);
        mm64(W2 + HID * GATES, j, &hbuf[2][0][0], acc);
#pragma unroll
        for (int b = 0; b < BBLK; ++b) zbuf[b][j] = acc[b];
        __syncthreads();
        {
            const float hn = gatephase(&zbuf[bl][0], m, c2);
            hbuf[2][bl][m] = hn;
        }
        __syncthreads();

        // ---------------- layer 3 : in = [h2, h3] + LN + proj ----------------
#pragma unroll
        for (int b = 0; b < BBLK; ++b) acc[b] = bias3;
        mm64(W3,              j, &hbuf[2][0][0], acc);
        mm64(W3 + HID * GATES, j, &hbuf[3][0][0], acc);
#pragma unroll
        for (int b = 0; b < BBLK; ++b) zbuf[b][j] = acc[b];
        __syncthreads();
        {
            const float hn = gatephase(&zbuf[bl][0], m, c3);
            hbuf[3][bl][m] = hn;

            // fused LayerNorm + out-projection over the wave (64 lanes = 64 hidden)
            float s1 = hn, s2 = hn * hn;
#pragma unroll
            for (int off = 32; off > 0; off >>= 1) {
                s1 += __shfl_xor(s1, off, 64);
                s2 += __shfl_xor(s2, off, 64);
            }
            const float mu  = s1 * (1.0f / HID);
            float var = fmaf(s2, 1.0f / HID, -mu * mu);
            var = fmaxf(var, 0.0f);
            const float rs = rsqrtf(var + 1e-5f);
            float contrib = fmaf((hn - mu) * rs, gam, bet) * wo;
#pragma unroll
            for (int off = 32; off > 0; off >>= 1)
                contrib += __shfl_xor(contrib, off, 64);
            if (m == 0)
                out[(bb * BBLK + bl) * SEQ + t] = contrib + bo;
        }
        __syncthreads();
    }
}

extern "C" void kernel_launch(void* const* d_in, const int* in_sizes, int n_in,
                              void* d_out, int out_size, void* d_ws, size_t ws_size,
                              hipStream_t stream)
{
    const float* x    = (const float*)d_in[0];
    const float* W0   = (const float*)d_in[1];
    const float* B0   = (const float*)d_in[2];
    const float* W1   = (const float*)d_in[3];
    const float* B1   = (const float*)d_in[4];
    const float* W2   = (const float*)d_in[5];
    const float* B2   = (const float*)d_in[6];
    const float* W3   = (const float*)d_in[7];
    const float* B3   = (const float*)d_in[8];
    const float* ln_g = (const float*)d_in[9];
    const float* ln_b = (const float*)d_in[10];
    const float* Wout = (const float*)d_in[11];
    const float* bout = (const float*)d_in[12];
    float* out = (float*)d_out;

    lstm4_f32<<<NBLK, 256, 0, stream>>>(x, W0, B0, W1, B1, W2, B2, W3, B3,
                                        ln_g, ln_b, Wout, bout, out);
}

// Round 2
// 3302.304 us; speedup vs baseline: 2.7253x; 2.7253x over previous
//
#include <hip/hip_runtime.h>
#include <hip/hip_fp16.h>

#define HID   64
#define SEQ   512
#define BBLK  4
#define GATES 256   // 4*HID
#define NTHR  512
#define NBLK  256   // 1024 batch / BBLK

__device__ __forceinline__ float sig_(float x) { return 1.0f / (1.0f + __expf(-x)); }

// sign-stable tanh
__device__ __forceinline__ float tanh_(float x) {
    const float e = __expf(-2.0f * fabsf(x));
    const float r = (1.0f - e) / (1.0f + e);
    return copysignf(r, x);
}

__global__ __launch_bounds__(NTHR, 2) void lstm4_regw(
    const float* __restrict__ x,
    const float* __restrict__ W0, const float* __restrict__ B0,
    const float* __restrict__ W1, const float* __restrict__ B1,
    const float* __restrict__ W2, const float* __restrict__ B2,
    const float* __restrict__ W3, const float* __restrict__ B3,
    const float* __restrict__ ln_g, const float* __restrict__ ln_b,
    const float* __restrict__ Wout, const float* __restrict__ bout,
    float* __restrict__ out)
{
    __shared__ float hbuf[4][HID][BBLK];     // transposed: [layer][k][b]
    __shared__ float zpart[2][BBLK][GATES];  // k-split partial gate sums
    __shared__ float xall[BBLK][SEQ];

    const int tid = threadIdx.x;
    const int j   = tid & 255;   // gate column
    const int q   = tid >> 8;    // k-split half (wave-uniform)
    const int bb  = blockIdx.x;

    // ---- stage x ----
    for (int i = tid; i < BBLK * SEQ; i += NTHR) {
        const int b = i >> 9, t = i & 511;
        xall[b][t] = x[(bb * BBLK + b) * SEQ + t];
    }
    // ---- zero h state ----
    for (int i = tid; i < 4 * HID * BBLK; i += NTHR)
        (&hbuf[0][0][0])[i] = 0.0f;

    // ---- load weights into registers (f16-packed, 2 per VGPR) ----
    const float wx0 = W0[j];
    const float bj0 = B0[j], bj1 = B1[j], bj2 = B2[j], bj3 = B3[j];

    __half2 w0h[16];
#pragma unroll
    for (int kk = 0; kk < 16; ++kk) {
        const int row = 1 + q * 32 + 2 * kk;        // W0 rows 1..64 are h-weights
        w0h[kk] = __floats2half2_rn(W0[row * GATES + j], W0[(row + 1) * GATES + j]);
    }
    __half2 w1[32], w2[32], w3[32];
#pragma unroll
    for (int kk = 0; kk < 32; ++kk) {
        const int row = q * 64 + 2 * kk;            // rows 0..63 = h_in, 64..127 = h_self
        w1[kk] = __floats2half2_rn(W1[row * GATES + j], W1[(row + 1) * GATES + j]);
        w2[kk] = __floats2half2_rn(W2[row * GATES + j], W2[(row + 1) * GATES + j]);
        w3[kk] = __floats2half2_rn(W3[row * GATES + j], W3[(row + 1) * GATES + j]);
    }

    // gate-phase thread constants (tid < 256: (bl, m) owner)
    const int bl = (tid >> 6) & 3;
    const int m  = tid & 63;
    const float gam = ln_g[m], bet = ln_b[m], wo = Wout[m], bo = bout[0];
    float cL0 = 0.0f, cL1 = 0.0f, cL2 = 0.0f, cL3 = 0.0f;

    __syncthreads();

    for (int t = 0; t < SEQ; ++t) {
        float a0, a1, a2, a3;

        // ================= layer 0 =================
        if (q == 0) {
            a0 = fmaf(xall[0][t], wx0, bj0);
            a1 = fmaf(xall[1][t], wx0, bj0);
            a2 = fmaf(xall[2][t], wx0, bj0);
            a3 = fmaf(xall[3][t], wx0, bj0);
        } else { a0 = a1 = a2 = a3 = 0.0f; }
        {
            const float* hs = &hbuf[0][q * 32][0];
#pragma unroll
            for (int kk = 0; kk < 16; ++kk) {
                const float2 w = __half22float2(w0h[kk]);
                const float4 hA = *reinterpret_cast<const float4*>(hs + (2 * kk) * BBLK);
                const float4 hB = *reinterpret_cast<const float4*>(hs + (2 * kk + 1) * BBLK);
                a0 = fmaf(w.x, hA.x, a0); a1 = fmaf(w.x, hA.y, a1);
                a2 = fmaf(w.x, hA.z, a2); a3 = fmaf(w.x, hA.w, a3);
                a0 = fmaf(w.y, hB.x, a0); a1 = fmaf(w.y, hB.y, a1);
                a2 = fmaf(w.y, hB.z, a2); a3 = fmaf(w.y, hB.w, a3);
            }
        }
        zpart[q][0][j] = a0; zpart[q][1][j] = a1;
        zpart[q][2][j] = a2; zpart[q][3][j] = a3;
        __syncthreads();
        if (tid < 256) {
            const float zi = zpart[0][bl][m]       + zpart[1][bl][m];
            const float zf = zpart[0][bl][m + 64]  + zpart[1][bl][m + 64];
            const float zg = zpart[0][bl][m + 128] + zpart[1][bl][m + 128];
            const float zo = zpart[0][bl][m + 192] + zpart[1][bl][m + 192];
            cL0 = fmaf(sig_(zf), cL0, sig_(zi) * tanh_(zg));
            hbuf[0][m][bl] = sig_(zo) * tanh_(cL0);
        }
        __syncthreads();

        // ================= layers 1..3 =================
#define LAYER(L, WREG, BJ, CST)                                                   \
        {                                                                          \
            a0 = (q == 0) ? BJ : 0.0f; a1 = a0; a2 = a0; a3 = a0;                  \
            const float* hs = (q == 0) ? &hbuf[L - 1][0][0] : &hbuf[L][0][0];      \
            _Pragma("unroll")                                                      \
            for (int kk = 0; kk < 32; ++kk) {                                      \
                const float2 w = __half22float2(WREG[kk]);                         \
                const float4 hA = *reinterpret_cast<const float4*>(hs + (2*kk)*BBLK);   \
                const float4 hB = *reinterpret_cast<const float4*>(hs + (2*kk+1)*BBLK); \
                a0 = fmaf(w.x, hA.x, a0); a1 = fmaf(w.x, hA.y, a1);                \
                a2 = fmaf(w.x, hA.z, a2); a3 = fmaf(w.x, hA.w, a3);                \
                a0 = fmaf(w.y, hB.x, a0); a1 = fmaf(w.y, hB.y, a1);                \
                a2 = fmaf(w.y, hB.z, a2); a3 = fmaf(w.y, hB.w, a3);                \
            }                                                                      \
            zpart[q][0][j] = a0; zpart[q][1][j] = a1;                              \
            zpart[q][2][j] = a2; zpart[q][3][j] = a3;                              \
            __syncthreads();                                                       \
            if (tid < 256) {                                                       \
                const float zi = zpart[0][bl][m]       + zpart[1][bl][m];          \
                const float zf = zpart[0][bl][m + 64]  + zpart[1][bl][m + 64];     \
                const float zg = zpart[0][bl][m + 128] + zpart[1][bl][m + 128];    \
                const float zo = zpart[0][bl][m + 192] + zpart[1][bl][m + 192];    \
                CST = fmaf(sig_(zf), CST, sig_(zi) * tanh_(zg));                   \
                hbuf[L][m][bl] = sig_(zo) * tanh_(CST);                            \
            }                                                                      \
        }

        LAYER(1, w1, bj1, cL1)
        __syncthreads();
        LAYER(2, w2, bj2, cL2)
        __syncthreads();

        // layer 3: fuse LN + projection into the gate phase
        {
            a0 = (q == 0) ? bj3 : 0.0f; a1 = a0; a2 = a0; a3 = a0;
            const float* hs = (q == 0) ? &hbuf[2][0][0] : &hbuf[3][0][0];
#pragma unroll
            for (int kk = 0; kk < 32; ++kk) {
                const float2 w = __half22float2(w3[kk]);
                const float4 hA = *reinterpret_cast<const float4*>(hs + (2 * kk) * BBLK);
                const float4 hB = *reinterpret_cast<const float4*>(hs + (2 * kk + 1) * BBLK);
                a0 = fmaf(w.x, hA.x, a0); a1 = fmaf(w.x, hA.y, a1);
                a2 = fmaf(w.x, hA.z, a2); a3 = fmaf(w.x, hA.w, a3);
                a0 = fmaf(w.y, hB.x, a0); a1 = fmaf(w.y, hB.y, a1);
                a2 = fmaf(w.y, hB.z, a2); a3 = fmaf(w.y, hB.w, a3);
            }
            zpart[q][0][j] = a0; zpart[q][1][j] = a1;
            zpart[q][2][j] = a2; zpart[q][3][j] = a3;
            __syncthreads();
            if (tid < 256) {
                const float zi = zpart[0][bl][m]       + zpart[1][bl][m];
                const float zf = zpart[0][bl][m + 64]  + zpart[1][bl][m + 64];
                const float zg = zpart[0][bl][m + 128] + zpart[1][bl][m + 128];
                const float zo = zpart[0][bl][m + 192] + zpart[1][bl][m + 192];
                cL3 = fmaf(sig_(zf), cL3, sig_(zi) * tanh_(zg));
                const float hn = sig_(zo) * tanh_(cL3);
                hbuf[3][m][bl] = hn;

                float s1 = hn, s2 = hn * hn;
#pragma unroll
                for (int off = 32; off > 0; off >>= 1) {
                    s1 += __shfl_xor(s1, off, 64);
                    s2 += __shfl_xor(s2, off, 64);
                }
                const float mu = s1 * (1.0f / HID);
                float var = fmaf(s2, 1.0f / HID, -mu * mu);
                var = fmaxf(var, 0.0f);
                const float rs = rsqrtf(var + 1e-5f);
                float contrib = fmaf((hn - mu) * rs, gam, bet) * wo;
#pragma unroll
                for (int off = 32; off > 0; off >>= 1)
                    contrib += __shfl_xor(contrib, off, 64);
                if (m == 0)
                    out[(bb * BBLK + bl) * SEQ + t] = contrib + bo;
            }
        }
        __syncthreads();
    }
#undef LAYER
}

extern "C" void kernel_launch(void* const* d_in, const int* in_sizes, int n_in,
                              void* d_out, int out_size, void* d_ws, size_t ws_size,
                              hipStream_t stream)
{
    const float* x    = (const float*)d_in[0];
    const float* W0   = (const float*)d_in[1];
    const float* B0   = (const float*)d_in[2];
    const float* W1   = (const float*)d_in[3];
    const float* B1   = (const float*)d_in[4];
    const float* W2   = (const float*)d_in[5];
    const float* B2   = (const float*)d_in[6];
    const float* W3   = (const float*)d_in[7];
    const float* B3   = (const float*)d_in[8];
    const float* ln_g = (const float*)d_in[9];
    const float* ln_b = (const float*)d_in[10];
    const float* Wout = (const float*)d_in[11];
    const float* bout = (const float*)d_in[12];
    float* out = (float*)d_out;

    lstm4_regw<<<NBLK, NTHR, 0, stream>>>(x, W0, B0, W1, B1, W2, B2, W3, B3,
                                          ln_g, ln_b, Wout, bout, out);
}